// Round 11
// baseline (238.986 us; speedup 1.0000x reference)
//
#include <hip/hip_runtime.h>

typedef float floatx4 __attribute__((ext_vector_type(4)));
typedef _Float16 half2v __attribute__((ext_vector_type(2)));
typedef _Float16 half8 __attribute__((ext_vector_type(8)));

#define Hh 128
#define Ww 256
#define Cc 64
#define COUT 64
#define Bb 4
#define HW (Hh*Ww)
#define VP 74   // LDS V row stride in shorts: 37 dwords ≡ 5 (mod 32) -> <=2-way (free)

// prep (R6, verified, unchanged).
__launch_bounds__(512, 4)
__global__ void prep(const float* __restrict__ x, const float* __restrict__ wsrc,
                     _Float16* __restrict__ xn, unsigned short* __restrict__ wdst) {
    const int bid = blockIdx.x;
    const int tid = threadIdx.x;
    if (bid >= 512) {   // weight repack -> fragment-major [kt][mbh][j][ln][8]
        const int i = (bid - 512) * 72 + tid;
        if (tid < 72) {
            const int kt = i % 9, c = (i / 9) % Cc, o = i / (9 * Cc);
            const int mbh = o >> 5, mi = (o >> 4) & 1, r = o & 15;
            const int g = c >> 5, ks = (c >> 3) & 3, s = c & 7;
            const int ln = ks * 16 + r, j = g * 2 + mi;
            _Float16 hv = (_Float16)wsrc[i];
            wdst[(((kt * 2 + mbh) * 4 + j) * 64 + ln) * 8 + s] = *(unsigned short*)&hv;
        }
        return;
    }
    const int cg = bid >> 6;
    const int T  = bid & 63;
    const int b  = T >> 4;
    const int ht = T & 15;
    __shared__ float Tf[64][260];
    const float* src = x + ((size_t)(b * Cc + cg * 8) * Hh + ht * 8) * Ww;
#pragma unroll
    for (int s = 0; s < 8; ++s) {
        const int u   = s * 512 + tid;
        const int row = u >> 6;
        const int wq  = u & 63;
        const float4 v = *(const float4*)(src + (size_t)(row >> 3) * HW + (row & 7) * Ww + wq * 4);
        *(float4*)&Tf[row][wq * 4] = v;
    }
    __syncthreads();
#pragma unroll
    for (int j2 = 0; j2 < 4; ++j2) {
        const int idx = j2 * 512 + tid;
        const int hh = idx >> 8, w = idx & 255;
        unsigned o4[4];
#pragma unroll
        for (int cp = 0; cp < 4; ++cp) {
            half2v hv;
            hv.x = (_Float16)Tf[(2 * cp) * 8 + hh][w];
            hv.y = (_Float16)Tf[(2 * cp + 1) * 8 + hh][w];
            o4[cp] = *(unsigned*)&hv;
        }
        uint4 u4; u4.x = o4[0]; u4.y = o4[1]; u4.z = o4[2]; u4.w = o4[3];
        *(uint4*)(xn + ((size_t)(b * Hh + ht * 8 + hh) * Ww + w) * 64 + cg * 8) = u4;
    }
}

// lgkm-only barrier: in-flight VMEM survives (R6 verified).
__device__ __forceinline__ void lds_barrier() {
    asm volatile("s_waitcnt lgkmcnt(0)\n\ts_barrier" ::: "memory");
}

struct Tap {
    half2v W00, W01, W10, W11;
    int a00, a01, a10, a11;
};

template<int I>
__device__ __forceinline__ unsigned (&sel3(unsigned (&a)[16], unsigned (&b)[16],
                                           unsigned (&c)[16]))[16] {
    if constexpr (I == 0) return a; else if constexpr (I == 1) return b; else return c;
}
template<int I>
__device__ __forceinline__ Tap& sel3t(Tap& a, Tap& b, Tap& c) {
    if constexpr (I == 0) return a; else if constexpr (I == 1) return b; else return c;
}

__device__ __forceinline__ void tap_setup(int kt, int h, int w, float dy, float dx,
                                          int cg, Tap& t) {
    const int ki = kt / 3, kj = kt % 3;
    const float py = (float)(h - 1 + ki) + dy;
    const float px = (float)(w - 1 + kj) + dx;
    const float y0f = floorf(py), x0f = floorf(px);
    const int y0 = (int)y0f, x0 = (int)x0f;
    const float ly = py - y0f, lx = px - x0f;
    const int y1 = y0 + 1, x1 = x0 + 1;
    const bool vy0 = ((unsigned)y0 < Hh), vy1 = ((unsigned)y1 < Hh);
    const bool vx0 = ((unsigned)x0 < Ww), vx1 = ((unsigned)x1 < Ww);
    const float w00 = (vy0 && vx0) ? (1.f - ly) * (1.f - lx) : 0.f;
    const float w01 = (vy0 && vx1) ? (1.f - ly) * lx : 0.f;
    const float w10 = (vy1 && vx0) ? ly * (1.f - lx) : 0.f;
    const float w11 = (vy1 && vx1) ? ly * lx : 0.f;
    _Float16 h00 = (_Float16)w00, h01 = (_Float16)w01;
    _Float16 h10 = (_Float16)w10, h11 = (_Float16)w11;
    t.W00.x = h00; t.W00.y = h00;  t.W01.x = h01; t.W01.y = h01;
    t.W10.x = h10; t.W10.y = h10;  t.W11.x = h11; t.W11.y = h11;
    const int y0c = min(max(y0, 0), Hh - 1), y1c = min(max(y1, 0), Hh - 1);
    const int x0c = min(max(x0, 0), Ww - 1), x1c = min(max(x1, 0), Ww - 1);
    t.a00 = (y0c * Ww + x0c) * 8 + cg;
    t.a01 = (y0c * Ww + x1c) * 8 + cg;
    t.a10 = (y1c * Ww + x0c) * 8 + cg;
    t.a11 = (y1c * Ww + x1c) * 8 + cg;
}

__device__ __forceinline__ void tap_load(const uint4* __restrict__ xb4, const Tap& t,
                                         unsigned (&pf)[16]) {
    *(uint4*)&pf[0]  = xb4[t.a00];
    *(uint4*)&pf[4]  = xb4[t.a01];
    *(uint4*)&pf[8]  = xb4[t.a10];
    *(uint4*)&pf[12] = xb4[t.a11];
}

// R6-exact weight fragment load (fragment-major; wave-pair L1 broadcast)
__device__ __forceinline__ void wf_load(const unsigned short* __restrict__ wt,
                                        half8 (&WF)[4]) {
    WF[0] = *(const half8*)(wt);
    WF[1] = *(const half8*)(wt + 512);
    WF[2] = *(const half8*)(wt + 1024);
    WF[3] = *(const half8*)(wt + 1536);
}

__device__ __forceinline__ void tap_store(const Tap& t, const unsigned (&pf)[16],
                                          unsigned short* __restrict__ vrow) {
    unsigned o[4];
#pragma unroll
    for (int s = 0; s < 4; ++s) {
        half2v v = (*(const half2v*)&pf[s])      * t.W00
                 + (*(const half2v*)&pf[4 + s])  * t.W01
                 + (*(const half2v*)&pf[8 + s])  * t.W10
                 + (*(const half2v*)&pf[12 + s]) * t.W11;
        o[s] = *(unsigned*)&v;
    }
    uint4 u; u.x = o[0]; u.y = o[1]; u.z = o[2]; u.w = o[3];
    *(uint4*)vrow = u;
}

// R6-exact mfma (2 bfrag ds_reads, 4 MFMAs; wave = 2 m-tiles x 1 n-tile)
__device__ __forceinline__ void mfma_tap(const half8 (&WF)[4],
                                         const unsigned short* __restrict__ Vbuf,
                                         int nt, int ln, floatx4 (&acc)[2]) {
#pragma unroll
    for (int g = 0; g < 2; ++g) {
        const int pp = nt * 16 + (ln & 15);
        half8 bfrag = *(const half8*)&Vbuf[pp * VP + g * 32 + (ln >> 4) * 8];
        acc[0] = __builtin_amdgcn_mfma_f32_16x16x32_f16(WF[2 * g],     bfrag, acc[0], 0, 0, 0);
        acc[1] = __builtin_amdgcn_mfma_f32_16x16x32_f16(WF[2 * g + 1], bfrag, acc[1], 0, 0, 0);
    }
}

// R10 ablation of the R6-EXACT pipeline.
// MODE 0 = full (R6-exact, correct output, launched LAST)
// MODE 1 = skel: steady-state gathers+setup+offset reads removed (pf/Tap
//          frozen from prologue -> defined, no poison/DCE; pack->V->MFMA live)
// MODE 2 = nowt: steady-state wf_load removed (WF frozen from prologue)
template<int KT, int MODE>
__device__ __forceinline__ void pipe_iter(
    const uint4* __restrict__ xb4, const float* __restrict__ offb,
    const unsigned short* __restrict__ wfb,
    const unsigned short* __restrict__ V0, const unsigned short* __restrict__ V1,
    unsigned short* __restrict__ vrow0, unsigned short* __restrict__ vrow1,
    int h, int w, int cg, int nt, int ln,
    Tap& tpA, Tap& tpB, Tap& tpC,
    unsigned (&pfA)[16], unsigned (&pfB)[16], unsigned (&pfC)[16],
    half8 (&WF0)[4], half8 (&WF1)[4],
    float& dy0, float& dx0, float& dy1, float& dx1,
    floatx4 (&acc)[2])
{
    constexpr int S = KT & 1;
    // 1. weight frags for tap KT (consumed at iter KT+1 / epilogue)
    if constexpr (MODE != 2)
        wf_load(wfb + KT * 4096, S ? WF1 : WF0);
    // 2. gathers for tap KT+2 -> slot (KT+2)%3; offset slot S
    if constexpr (MODE != 1) {
        if constexpr (KT + 2 <= 8) {
            constexpr int GI = (KT + 2) % 3;
            Tap& tg = sel3t<GI>(tpA, tpB, tpC);
            tap_setup(KT + 2, h, w, S ? dy1 : dy0, S ? dx1 : dx0, cg, tg);
            tap_load(xb4, tg, sel3<GI>(pfA, pfB, pfC));
        }
        // 3. offset refill for tap KT+4 into slot S
        if constexpr (KT + 4 <= 8) {
            (S ? dy1 : dy0) = offb[(2 * (KT + 4)) * HW];
            (S ? dx1 : dx0) = offb[(2 * (KT + 4) + 1) * HW];
        }
    }
    // 4. MFMA tap KT-1
    constexpr int Tm = 1 - S;
    mfma_tap(Tm ? WF1 : WF0, Tm ? V1 : V0, nt, ln, acc);
    // 5. combine+pack tap KT into V[S] (pf slot KT%3)
    constexpr int SI = KT % 3;
    tap_store(sel3t<SI>(tpA, tpB, tpC), sel3<SI>(pfA, pfB, pfC),
              S ? vrow1 : vrow0);
    // 6. barrier (lgkm only; VMEM prefetches stay in flight)
    lds_barrier();
}

template<int MODE>
__device__ __forceinline__ void dcn_body(const _Float16* __restrict__ xn,
                                         const float* __restrict__ offset,
                                         const unsigned short* __restrict__ wb,
                                         const float* __restrict__ bias,
                                         float* __restrict__ out) {
    __shared__ unsigned short V[2][32 * VP];   // 2 x 4736 B (R6-exact)

    const int tid = threadIdx.x;
    const int p   = tid >> 3;
    const int cg  = tid & 7;
    const int wv  = tid >> 6;
    const int ln  = tid & 63;

    const int b  = blockIdx.z;
    const int h  = blockIdx.y;
    const int w0 = blockIdx.x * 32;
    const int w  = w0 + p;

    const uint4* xb4  = (const uint4*)(xn + (size_t)b * HW * 64);
    const float* offb = offset + b * 18 * HW + h * Ww + w;
    unsigned short* vrow0 = &V[0][p * VP + cg * 8];
    unsigned short* vrow1 = &V[1][p * VP + cg * 8];

    const int nt = wv & 1;
    const int mb = (wv >> 1) * 2;
    const unsigned short* wfb = wb + (wv >> 1) * 2048 + ln * 8;

    floatx4 acc[2];
    acc[0] = (floatx4)0.f; acc[1] = (floatx4)0.f;

    unsigned pfA[16], pfB[16], pfC[16];
    half8 WF0[4], WF1[4];
    Tap tpA, tpB, tpC;

    // prologue (R6-exact for MODE 0/2; MODE 1 uses zero offsets, one-time)
    float dy0 = 0.f, dx0 = 0.f, dy1 = 0.f, dx1 = 0.f;
    if constexpr (MODE != 1) {
        dy0 = offb[0];        dx0 = offb[HW];
        dy1 = offb[2 * HW];   dx1 = offb[3 * HW];
    }
    wf_load(wfb, WF0);                                  // WF(0)
    if constexpr (MODE == 2) wf_load(wfb + 4096, WF1);  // keep WF1 defined
    tap_setup(0, h, w, dy0, dx0, cg, tpA);
    tap_load(xb4, tpA, pfA);
    tap_setup(1, h, w, dy1, dx1, cg, tpB);
    tap_load(xb4, tpB, pfB);
    if constexpr (MODE != 1) {
        dy0 = offb[4 * HW]; dx0 = offb[5 * HW];
        dy1 = offb[6 * HW]; dx1 = offb[7 * HW];
    }
    tap_setup(2, h, w, dy0, dx0, cg, tpC);
    tap_load(xb4, tpC, pfC);
    if constexpr (MODE != 1) { dy0 = offb[8 * HW]; dx0 = offb[9 * HW]; }
    tap_store(tpA, pfA, vrow0);
    lds_barrier();

#define PI(K) pipe_iter<K, MODE>(xb4, offb, wfb, V[0], V[1], vrow0, vrow1, h, w, cg, nt, ln, \
                                 tpA, tpB, tpC, pfA, pfB, pfC, WF0, WF1,                     \
                                 dy0, dx0, dy1, dx1, acc)
    PI(1); PI(2); PI(3); PI(4); PI(5); PI(6); PI(7); PI(8);
#undef PI

    // epilogue (R6-exact)
    mfma_tap(WF0, V[0], nt, ln, acc);

    float* outp = out + b * COUT * HW + h * Ww;
    const int col = w0 + nt * 16 + (ln & 15);
#pragma unroll
    for (int mi = 0; mi < 2; ++mi)
#pragma unroll
        for (int r = 0; r < 4; ++r) {
            const int o = (mb + mi) * 16 + (ln >> 4) * 4 + r;
            outp[o * HW + col] = acc[mi][r] + bias[o];
        }
}

// anchor, R6-exact, correct output (launched LAST)
__launch_bounds__(256, 4)
__global__ void dcn_full(const _Float16* __restrict__ xn, const float* __restrict__ offset,
                         const unsigned short* __restrict__ wb, const float* __restrict__ bias,
                         float* __restrict__ out) {
    dcn_body<0>(xn, offset, wb, bias, out);
}
// ablation: no steady-state gathers/setup/offsets
__launch_bounds__(256, 4)
__global__ void dcn_skel(const _Float16* __restrict__ xn, const float* __restrict__ offset,
                         const unsigned short* __restrict__ wb, const float* __restrict__ bias,
                         float* __restrict__ out) {
    dcn_body<1>(xn, offset, wb, bias, out);
}
// ablation: no steady-state weight loads
__launch_bounds__(256, 4)
__global__ void dcn_nowt(const _Float16* __restrict__ xn, const float* __restrict__ offset,
                         const unsigned short* __restrict__ wb, const float* __restrict__ bias,
                         float* __restrict__ out) {
    dcn_body<2>(xn, offset, wb, bias, out);
}

extern "C" void kernel_launch(void* const* d_in, const int* in_sizes, int n_in,
                              void* d_out, int out_size, void* d_ws, size_t ws_size,
                              hipStream_t stream) {
    const float* x      = (const float*)d_in[0];
    const float* offset = (const float*)d_in[1];
    const float* weight = (const float*)d_in[2];
    const float* bias   = (const float*)d_in[3];
    float* out = (float*)d_out;

    _Float16* xn = (_Float16*)d_ws;                          // 16.8 MiB NHWC fp16
    unsigned short* wb = (unsigned short*)((char*)d_ws + (size_t)Bb * HW * Cc * 2);

    prep<<<dim3(1024), 512, 0, stream>>>(x, weight, xn, wb);

    const dim3 g(Ww / 32, Hh, Bb), blk(256);
    // ablations (wrong output, overwritten by final dispatch):
    dcn_nowt<<<g, blk, 0, stream>>>(xn, offset, wb, bias, out);
    dcn_skel<<<g, blk, 0, stream>>>(xn, offset, wb, bias, out);
    // anchor + verified output:
    dcn_full<<<g, blk, 0, stream>>>(xn, offset, wb, bias, out);
}

// Round 14
// 186.674 us; speedup vs baseline: 1.2802x; 1.2802x over previous
//
#include <hip/hip_runtime.h>

typedef float floatx4 __attribute__((ext_vector_type(4)));
typedef _Float16 half2v __attribute__((ext_vector_type(2)));
typedef _Float16 half8 __attribute__((ext_vector_type(8)));

#define Hh 128
#define Ww 256
#define Cc 64
#define COUT 64
#define Bb 4
#define HW (Hh*Ww)
#define VP 74   // LDS V row stride in shorts: 37 dwords ≡ 5 (mod 32) -> <=2-way (free)

// prep (R6, verified, unchanged).
__launch_bounds__(512, 4)
__global__ void prep(const float* __restrict__ x, const float* __restrict__ wsrc,
                     _Float16* __restrict__ xn, unsigned short* __restrict__ wdst) {
    const int bid = blockIdx.x;
    const int tid = threadIdx.x;
    if (bid >= 512) {   // weight repack -> fragment-major [kt][mbh][j][ln][8]
        const int i = (bid - 512) * 72 + tid;
        if (tid < 72) {
            const int kt = i % 9, c = (i / 9) % Cc, o = i / (9 * Cc);
            const int mbh = o >> 5, mi = (o >> 4) & 1, r = o & 15;
            const int g = c >> 5, ks = (c >> 3) & 3, s = c & 7;
            const int ln = ks * 16 + r, j = g * 2 + mi;
            _Float16 hv = (_Float16)wsrc[i];
            wdst[(((kt * 2 + mbh) * 4 + j) * 64 + ln) * 8 + s] = *(unsigned short*)&hv;
        }
        return;
    }
    const int cg = bid >> 6;
    const int T  = bid & 63;
    const int b  = T >> 4;
    const int ht = T & 15;
    __shared__ float Tf[64][260];
    const float* src = x + ((size_t)(b * Cc + cg * 8) * Hh + ht * 8) * Ww;
#pragma unroll
    for (int s = 0; s < 8; ++s) {
        const int u   = s * 512 + tid;
        const int row = u >> 6;
        const int wq  = u & 63;
        const float4 v = *(const float4*)(src + (size_t)(row >> 3) * HW + (row & 7) * Ww + wq * 4);
        *(float4*)&Tf[row][wq * 4] = v;
    }
    __syncthreads();
#pragma unroll
    for (int j2 = 0; j2 < 4; ++j2) {
        const int idx = j2 * 512 + tid;
        const int hh = idx >> 8, w = idx & 255;
        unsigned o4[4];
#pragma unroll
        for (int cp = 0; cp < 4; ++cp) {
            half2v hv;
            hv.x = (_Float16)Tf[(2 * cp) * 8 + hh][w];
            hv.y = (_Float16)Tf[(2 * cp + 1) * 8 + hh][w];
            o4[cp] = *(unsigned*)&hv;
        }
        uint4 u4; u4.x = o4[0]; u4.y = o4[1]; u4.z = o4[2]; u4.w = o4[3];
        *(uint4*)(xn + ((size_t)(b * Hh + ht * 8 + hh) * Ww + w) * 64 + cg * 8) = u4;
    }
}

// lgkm-only barrier (R6 verified).
__device__ __forceinline__ void lds_barrier() {
    asm volatile("s_waitcnt lgkmcnt(0)\n\ts_barrier" ::: "memory");
}

struct Tap {
    half2v W00, W01, W10, W11;
    int a00, a01, a10, a11;
};

template<int I>
__device__ __forceinline__ unsigned (&sel3(unsigned (&a)[16], unsigned (&b)[16],
                                           unsigned (&c)[16]))[16] {
    if constexpr (I == 0) return a; else if constexpr (I == 1) return b; else return c;
}
template<int I>
__device__ __forceinline__ Tap& sel3t(Tap& a, Tap& b, Tap& c) {
    if constexpr (I == 0) return a; else if constexpr (I == 1) return b; else return c;
}

__device__ __forceinline__ void tap_setup(int kt, int h, int w, float dy, float dx,
                                          int cg, Tap& t) {
    const int ki = kt / 3, kj = kt % 3;
    const float py = (float)(h - 1 + ki) + dy;
    const float px = (float)(w - 1 + kj) + dx;
    const float y0f = floorf(py), x0f = floorf(px);
    const int y0 = (int)y0f, x0 = (int)x0f;
    const float ly = py - y0f, lx = px - x0f;
    const int y1 = y0 + 1, x1 = x0 + 1;
    const bool vy0 = ((unsigned)y0 < Hh), vy1 = ((unsigned)y1 < Hh);
    const bool vx0 = ((unsigned)x0 < Ww), vx1 = ((unsigned)x1 < Ww);
    const float w00 = (vy0 && vx0) ? (1.f - ly) * (1.f - lx) : 0.f;
    const float w01 = (vy0 && vx1) ? (1.f - ly) * lx : 0.f;
    const float w10 = (vy1 && vx0) ? ly * (1.f - lx) : 0.f;
    const float w11 = (vy1 && vx1) ? ly * lx : 0.f;
    _Float16 h00 = (_Float16)w00, h01 = (_Float16)w01;
    _Float16 h10 = (_Float16)w10, h11 = (_Float16)w11;
    t.W00.x = h00; t.W00.y = h00;  t.W01.x = h01; t.W01.y = h01;
    t.W10.x = h10; t.W10.y = h10;  t.W11.x = h11; t.W11.y = h11;
    const int y0c = min(max(y0, 0), Hh - 1), y1c = min(max(y1, 0), Hh - 1);
    const int x0c = min(max(x0, 0), Ww - 1), x1c = min(max(x1, 0), Ww - 1);
    t.a00 = (y0c * Ww + x0c) * 8 + cg;
    t.a01 = (y0c * Ww + x1c) * 8 + cg;
    t.a10 = (y1c * Ww + x0c) * 8 + cg;
    t.a11 = (y1c * Ww + x1c) * 8 + cg;
}

__device__ __forceinline__ void tap_load(const uint4* __restrict__ xb4, const Tap& t,
                                         unsigned (&pf)[16]) {
    *(uint4*)&pf[0]  = xb4[t.a00];
    *(uint4*)&pf[4]  = xb4[t.a01];
    *(uint4*)&pf[8]  = xb4[t.a10];
    *(uint4*)&pf[12] = xb4[t.a11];
}

__device__ __forceinline__ void tap_store(const Tap& t, const unsigned (&pf)[16],
                                          unsigned short* __restrict__ vrow) {
    unsigned o[4];
#pragma unroll
    for (int s = 0; s < 4; ++s) {
        half2v v = (*(const half2v*)&pf[s])      * t.W00
                 + (*(const half2v*)&pf[4 + s])  * t.W01
                 + (*(const half2v*)&pf[8 + s])  * t.W10
                 + (*(const half2v*)&pf[12 + s]) * t.W11;
        o[s] = *(unsigned*)&v;
    }
    uint4 u; u.x = o[0]; u.y = o[1]; u.z = o[2]; u.w = o[3];
    *(uint4*)vrow = u;
}

// ---------------- R6-exact kernel (verified 58.8 us; anchor + output) -------

__device__ __forceinline__ void wf_load_r6(const unsigned short* __restrict__ wt,
                                           half8 (&WF)[4]) {
    WF[0] = *(const half8*)(wt);
    WF[1] = *(const half8*)(wt + 512);
    WF[2] = *(const half8*)(wt + 1024);
    WF[3] = *(const half8*)(wt + 1536);
}

__device__ __forceinline__ void mfma_tap_r6(const half8 (&WF)[4],
                                            const unsigned short* __restrict__ Vbuf,
                                            int nt, int ln, floatx4 (&acc)[2]) {
#pragma unroll
    for (int g = 0; g < 2; ++g) {
        const int pp = nt * 16 + (ln & 15);
        half8 bfrag = *(const half8*)&Vbuf[pp * VP + g * 32 + (ln >> 4) * 8];
        acc[0] = __builtin_amdgcn_mfma_f32_16x16x32_f16(WF[2 * g],     bfrag, acc[0], 0, 0, 0);
        acc[1] = __builtin_amdgcn_mfma_f32_16x16x32_f16(WF[2 * g + 1], bfrag, acc[1], 0, 0, 0);
    }
}

template<int KT>
__device__ __forceinline__ void pipe_iter_r6(
    const uint4* __restrict__ xb4, const float* __restrict__ offb,
    const unsigned short* __restrict__ wfb,
    const unsigned short* __restrict__ V0, const unsigned short* __restrict__ V1,
    unsigned short* __restrict__ vrow0, unsigned short* __restrict__ vrow1,
    int h, int w, int cg, int nt, int ln,
    Tap& tpA, Tap& tpB, Tap& tpC,
    unsigned (&pfA)[16], unsigned (&pfB)[16], unsigned (&pfC)[16],
    half8 (&WF0)[4], half8 (&WF1)[4],
    float& dy0, float& dx0, float& dy1, float& dx1,
    floatx4 (&acc)[2])
{
    constexpr int S = KT & 1;
    wf_load_r6(wfb + KT * 4096, S ? WF1 : WF0);
    if constexpr (KT + 2 <= 8) {
        constexpr int GI = (KT + 2) % 3;
        Tap& tg = sel3t<GI>(tpA, tpB, tpC);
        tap_setup(KT + 2, h, w, S ? dy1 : dy0, S ? dx1 : dx0, cg, tg);
        tap_load(xb4, tg, sel3<GI>(pfA, pfB, pfC));
    }
    if constexpr (KT + 4 <= 8) {
        (S ? dy1 : dy0) = offb[(2 * (KT + 4)) * HW];
        (S ? dx1 : dx0) = offb[(2 * (KT + 4) + 1) * HW];
    }
    constexpr int Tm = 1 - S;
    mfma_tap_r6(Tm ? WF1 : WF0, Tm ? V1 : V0, nt, ln, acc);
    constexpr int SI = KT % 3;
    tap_store(sel3t<SI>(tpA, tpB, tpC), sel3<SI>(pfA, pfB, pfC),
              S ? vrow1 : vrow0);
    lds_barrier();
}

__launch_bounds__(256, 4)
__global__ void dcn_full(const _Float16* __restrict__ xn,
                         const float* __restrict__ offset,
                         const unsigned short* __restrict__ wb,
                         const float* __restrict__ bias,
                         float* __restrict__ out) {
    __shared__ unsigned short V[2][32 * VP];

    const int tid = threadIdx.x;
    const int p   = tid >> 3;
    const int cg  = tid & 7;
    const int wv  = tid >> 6;
    const int ln  = tid & 63;

    const int b  = blockIdx.z;
    const int h  = blockIdx.y;
    const int w0 = blockIdx.x * 32;
    const int w  = w0 + p;

    const uint4* xb4  = (const uint4*)(xn + (size_t)b * HW * 64);
    const float* offb = offset + b * 18 * HW + h * Ww + w;
    unsigned short* vrow0 = &V[0][p * VP + cg * 8];
    unsigned short* vrow1 = &V[1][p * VP + cg * 8];

    const int nt = wv & 1;
    const int mb = (wv >> 1) * 2;
    const unsigned short* wfb = wb + (wv >> 1) * 2048 + ln * 8;

    floatx4 acc[2];
    acc[0] = (floatx4)0.f; acc[1] = (floatx4)0.f;

    unsigned pfA[16], pfB[16], pfC[16];
    half8 WF0[4], WF1[4];
    Tap tpA, tpB, tpC;

    float dy0 = offb[0],        dx0 = offb[HW];
    float dy1 = offb[2 * HW],   dx1 = offb[3 * HW];
    wf_load_r6(wfb, WF0);
    tap_setup(0, h, w, dy0, dx0, cg, tpA);
    tap_load(xb4, tpA, pfA);
    tap_setup(1, h, w, dy1, dx1, cg, tpB);
    tap_load(xb4, tpB, pfB);
    dy0 = offb[4 * HW]; dx0 = offb[5 * HW];
    dy1 = offb[6 * HW]; dx1 = offb[7 * HW];
    tap_setup(2, h, w, dy0, dx0, cg, tpC);
    tap_load(xb4, tpC, pfC);
    dy0 = offb[8 * HW]; dx0 = offb[9 * HW];
    tap_store(tpA, pfA, vrow0);
    lds_barrier();

#define PI(K) pipe_iter_r6<K>(xb4, offb, wfb, V[0], V[1], vrow0, vrow1, h, w, cg, nt, ln, \
                              tpA, tpB, tpC, pfA, pfB, pfC, WF0, WF1,                     \
                              dy0, dx0, dy1, dx1, acc)
    PI(1); PI(2); PI(3); PI(4); PI(5); PI(6); PI(7); PI(8);
#undef PI

    mfma_tap_r6(WF0, V[0], nt, ln, acc);

    float* outp = out + b * COUT * HW + h * Ww;
    const int col = w0 + nt * 16 + (ln & 15);
#pragma unroll
    for (int mi = 0; mi < 2; ++mi)
#pragma unroll
        for (int r = 0; r < 4; ++r) {
            const int o = (mb + mi) * 16 + (ln >> 4) * 4 + r;
            outp[o * HW + col] = acc[mi][r] + bias[o];
        }
}

// ---------------- R11 barrier-free kernel (experiment; timing only) ---------

__device__ __forceinline__ void wf_load_all(const unsigned short* __restrict__ wt,
                                            half8 (&WF)[8]) {
#pragma unroll
    for (int mt = 0; mt < 4; ++mt)
#pragma unroll
        for (int g = 0; g < 2; ++g)
            WF[mt * 2 + g] = *(const half8*)(wt + (mt >> 1) * 2048 + (g * 2 + (mt & 1)) * 512);
}

__device__ __forceinline__ void mfma_all(const half8 (&WF)[8],
                                         const unsigned short* __restrict__ vread,
                                         floatx4 (&acc)[4]) {
#pragma unroll
    for (int g = 0; g < 2; ++g) {
        half8 bfrag = *(const half8*)(vread + g * 32);
#pragma unroll
        for (int mt = 0; mt < 4; ++mt)
            acc[mt] = __builtin_amdgcn_mfma_f32_16x16x32_f16(WF[mt * 2 + g], bfrag, acc[mt], 0, 0, 0);
    }
}

template<int T>
__device__ __forceinline__ void pipe_iter_bf(
    const uint4* __restrict__ xb4,
    const float* __restrict__ offb0, const float* __restrict__ offb1,
    const unsigned short* __restrict__ wfb,
    unsigned short* __restrict__ vw0a, unsigned short* __restrict__ vw1a,
    unsigned short* __restrict__ vw0b, unsigned short* __restrict__ vw1b,
    const unsigned short* __restrict__ vr_a, const unsigned short* __restrict__ vr_b,
    int h, int wA, int wB, int cg,
    Tap& tp0, Tap& tp1, unsigned (&pf0)[16], unsigned (&pf1)[16],
    half8 (&WF)[8],
    float& dy0a, float& dx0a, float& dy0b, float& dx0b,
    float& dy1a, float& dx1a, float& dy1b, float& dx1b,
    floatx4 (&acc)[4])
{
    constexpr int S = T & 1;
    wf_load_all(wfb + T * 4096, WF);
    tap_store(tp0, pf0, S ? vw0b : vw0a);
    tap_store(tp1, pf1, S ? vw1b : vw1a);
    if constexpr (T + 1 <= 8) {
        constexpr bool P = ((T + 1) & 1) != 0;
        tap_setup(T + 1, h, wA, P ? dy1a : dy0a, P ? dx1a : dx0a, cg, tp0);
        tap_setup(T + 1, h, wB, P ? dy1b : dy0b, P ? dx1b : dx0b, cg, tp1);
        tap_load(xb4, tp0, pf0);
        tap_load(xb4, tp1, pf1);
    }
    if constexpr (T + 2 <= 8) {
        if constexpr (S) {
            dy1a = offb0[(2 * (T + 2)) * HW];  dx1a = offb0[(2 * (T + 2) + 1) * HW];
            dy1b = offb1[(2 * (T + 2)) * HW];  dx1b = offb1[(2 * (T + 2) + 1) * HW];
        } else {
            dy0a = offb0[(2 * (T + 2)) * HW];  dx0a = offb0[(2 * (T + 2) + 1) * HW];
            dy0b = offb1[(2 * (T + 2)) * HW];  dx0b = offb1[(2 * (T + 2) + 1) * HW];
        }
    }
    mfma_all(WF, S ? vr_b : vr_a, acc);
}

__launch_bounds__(256, 3)
__global__ void dcn_bf(const _Float16* __restrict__ xn,
                       const float* __restrict__ offset,
                       const unsigned short* __restrict__ wb,
                       const float* __restrict__ bias,
                       float* __restrict__ out) {
    __shared__ unsigned short Vw[4][2][16 * VP];   // per-wave private dbuf

    const int tid = threadIdx.x;
    const int ln  = tid & 63;
    const int wv  = tid >> 6;
    const int sl  = ln >> 3;
    const int cg  = ln & 7;

    const int b  = blockIdx.z;
    const int h  = blockIdx.y;
    const int wp = blockIdx.x * 64 + wv * 16;
    const int wA = wp + sl;
    const int wB = wp + 8 + sl;

    const uint4* xb4  = (const uint4*)(xn + (size_t)b * HW * 64);
    const float* offb0 = offset + b * 18 * HW + h * Ww + wA;
    const float* offb1 = offset + b * 18 * HW + h * Ww + wB;
    const unsigned short* wfb = wb + ln * 8;

    unsigned short* vw0a = &Vw[wv][0][sl * VP + cg * 8];
    unsigned short* vw1a = &Vw[wv][0][(8 + sl) * VP + cg * 8];
    unsigned short* vw0b = &Vw[wv][1][sl * VP + cg * 8];
    unsigned short* vw1b = &Vw[wv][1][(8 + sl) * VP + cg * 8];
    const unsigned short* vr_a = &Vw[wv][0][(ln & 15) * VP + (ln >> 4) * 8];
    const unsigned short* vr_b = &Vw[wv][1][(ln & 15) * VP + (ln >> 4) * 8];

    floatx4 acc[4];
#pragma unroll
    for (int i = 0; i < 4; ++i) acc[i] = (floatx4)0.f;

    unsigned pf0[16], pf1[16];
    half8 WF[8];
    Tap tp0, tp1;

    float dy0a = offb0[0],      dx0a = offb0[HW];
    float dy0b = offb1[0],      dx0b = offb1[HW];
    float dy1a = offb0[2 * HW], dx1a = offb0[3 * HW];
    float dy1b = offb1[2 * HW], dx1b = offb1[3 * HW];
    tap_setup(0, h, wA, dy0a, dx0a, cg, tp0);
    tap_setup(0, h, wB, dy0b, dx0b, cg, tp1);
    tap_load(xb4, tp0, pf0);
    tap_load(xb4, tp1, pf1);

#define PI(K) pipe_iter_bf<K>(xb4, offb0, offb1, wfb, vw0a, vw1a, vw0b, vw1b,  \
                              vr_a, vr_b, h, wA, wB, cg, tp0, tp1, pf0, pf1,   \
                              WF, dy0a, dx0a, dy0b, dx0b, dy1a, dx1a, dy1b, dx1b, acc)
    PI(0); PI(1); PI(2); PI(3); PI(4); PI(5); PI(6); PI(7); PI(8);
#undef PI

    float* outp = out + b * COUT * HW + h * Ww;
    const int col = wp + (ln & 15);
#pragma unroll
    for (int mt = 0; mt < 4; ++mt)
#pragma unroll
        for (int r = 0; r < 4; ++r) {
            const int o = mt * 16 + (ln >> 4) * 4 + r;
            outp[o * HW + col] = acc[mt][r] + bias[o];
        }
}

extern "C" void kernel_launch(void* const* d_in, const int* in_sizes, int n_in,
                              void* d_out, int out_size, void* d_ws, size_t ws_size,
                              hipStream_t stream) {
    const float* x      = (const float*)d_in[0];
    const float* offset = (const float*)d_in[1];
    const float* weight = (const float*)d_in[2];
    const float* bias   = (const float*)d_in[3];
    float* out = (float*)d_out;

    _Float16* xn = (_Float16*)d_ws;                          // 16.8 MiB NHWC fp16
    unsigned short* wb = (unsigned short*)((char*)d_ws + (size_t)Bb * HW * Cc * 2);

    prep<<<dim3(1024), 512, 0, stream>>>(x, weight, xn, wb);

    // Experiment: barrier-free structure (timing only; output overwritten).
    dcn_bf<<<dim3(Ww / 64, Hh, Bb), 256, 0, stream>>>(xn, offset, wb, bias, out);
    // Anchor + verified output: R6-exact.
    dcn_full<<<dim3(Ww / 32, Hh, Bb), 256, 0, stream>>>(xn, offset, wb, bias, out);
}

// Round 15
// 144.360 us; speedup vs baseline: 1.6555x; 1.2931x over previous
//
#include <hip/hip_runtime.h>

typedef float floatx4 __attribute__((ext_vector_type(4)));
typedef _Float16 half2v __attribute__((ext_vector_type(2)));
typedef _Float16 half8 __attribute__((ext_vector_type(8)));

#define Hh 128
#define Ww 256
#define Cc 64
#define COUT 64
#define Bb 4
#define HW (Hh*Ww)
#define VP 74   // LDS V row stride in shorts: 37 dwords ≡ 5 (mod 32) -> <=2-way (free)

// prep (R6, verified): phase-1 streams 8KB contiguous runs; phase-2 emits
// NHWC 16B c-slices; same-XCD block swizzle merges interleaved output slices
// in one L2. Blocks >= 512: weight repack -> FRAGMENT-MAJOR [kt][mbh][j][ln][8]
// (the single biggest win of the session: dcn 94 -> 59 us).
__launch_bounds__(512, 4)
__global__ void prep(const float* __restrict__ x, const float* __restrict__ wsrc,
                     _Float16* __restrict__ xn, unsigned short* __restrict__ wdst) {
    const int bid = blockIdx.x;
    const int tid = threadIdx.x;
    if (bid >= 512) {   // weight repack: 512 blocks x 72 elems
        const int i = (bid - 512) * 72 + tid;
        if (tid < 72) { // i = o*576 + c*9 + kt
            const int kt = i % 9, c = (i / 9) % Cc, o = i / (9 * Cc);
            const int mbh = o >> 5, mi = (o >> 4) & 1, r = o & 15;
            const int g = c >> 5, ks = (c >> 3) & 3, s = c & 7;
            const int ln = ks * 16 + r, j = g * 2 + mi;
            _Float16 hv = (_Float16)wsrc[i];
            wdst[(((kt * 2 + mbh) * 4 + j) * 64 + ln) * 8 + s] = *(unsigned short*)&hv;
        }
        return;
    }
    const int cg = bid >> 6;          // channel group (8 ch)
    const int T  = bid & 63;          // tile
    const int b  = T >> 4;
    const int ht = T & 15;            // 8-row h tile
    __shared__ float Tf[64][260];
    const float* src = x + ((size_t)(b * Cc + cg * 8) * Hh + ht * 8) * Ww;
#pragma unroll
    for (int s = 0; s < 8; ++s) {
        const int u   = s * 512 + tid;      // 16B-unit index in [0,4096)
        const int row = u >> 6;             // c*8 + hh
        const int wq  = u & 63;
        const float4 v = *(const float4*)(src + (size_t)(row >> 3) * HW + (row & 7) * Ww + wq * 4);
        *(float4*)&Tf[row][wq * 4] = v;
    }
    __syncthreads();
#pragma unroll
    for (int j2 = 0; j2 < 4; ++j2) {
        const int idx = j2 * 512 + tid;     // hh*256 + w
        const int hh = idx >> 8, w = idx & 255;
        unsigned o4[4];
#pragma unroll
        for (int cp = 0; cp < 4; ++cp) {
            half2v hv;
            hv.x = (_Float16)Tf[(2 * cp) * 8 + hh][w];
            hv.y = (_Float16)Tf[(2 * cp + 1) * 8 + hh][w];
            o4[cp] = *(unsigned*)&hv;
        }
        uint4 u4; u4.x = o4[0]; u4.y = o4[1]; u4.z = o4[2]; u4.w = o4[3];
        *(uint4*)(xn + ((size_t)(b * Hh + ht * 8 + hh) * Ww + w) * 64 + cg * 8) = u4;
    }
}

// lgkm-only barrier: in-flight VMEM survives the barrier (verified R6).
// Session evidence for this structure (R7-R14 A/Bs, all within-probe):
//   - LDS-staged weights (vmcnt machinery): +5.7 us  -> reverted
//   - per-wave unique weight re-tiling:     +27.7 us -> reverted
//   - lag-2 MFMA / barriers halved:         +5.1 us  -> reverted
//   - zero-barrier wave-autonomous:         +1.5 us  -> reverted
// The ~43 us core cost is per-wave chain latency (gather->pack->LDS->MFMA),
// not inter-wave synchronization. This structure is its measured optimum.
__device__ __forceinline__ void lds_barrier() {
    asm volatile("s_waitcnt lgkmcnt(0)\n\ts_barrier" ::: "memory");
}

struct Tap {
    half2v W00, W01, W10, W11;   // packed (w,w) fp16 corner weights
    int a00, a01, a10, a11;      // corner addresses in uint4 (16B) units
};

// compile-time 3-way selectors (rule #20: never runtime-index register arrays)
template<int I>
__device__ __forceinline__ unsigned (&sel3(unsigned (&a)[16], unsigned (&b)[16],
                                           unsigned (&c)[16]))[16] {
    if constexpr (I == 0) return a; else if constexpr (I == 1) return b; else return c;
}
template<int I>
__device__ __forceinline__ Tap& sel3t(Tap& a, Tap& b, Tap& c) {
    if constexpr (I == 0) return a; else if constexpr (I == 1) return b; else return c;
}

__device__ __forceinline__ void tap_setup(int kt, int h, int w, float dy, float dx,
                                          int cg, Tap& t) {
    const int ki = kt / 3, kj = kt % 3;
    const float py = (float)(h - 1 + ki) + dy;
    const float px = (float)(w - 1 + kj) + dx;
    const float y0f = floorf(py), x0f = floorf(px);
    const int y0 = (int)y0f, x0 = (int)x0f;
    const float ly = py - y0f, lx = px - x0f;
    const int y1 = y0 + 1, x1 = x0 + 1;
    const bool vy0 = ((unsigned)y0 < Hh), vy1 = ((unsigned)y1 < Hh);
    const bool vx0 = ((unsigned)x0 < Ww), vx1 = ((unsigned)x1 < Ww);
    const float w00 = (vy0 && vx0) ? (1.f - ly) * (1.f - lx) : 0.f;
    const float w01 = (vy0 && vx1) ? (1.f - ly) * lx : 0.f;
    const float w10 = (vy1 && vx0) ? ly * (1.f - lx) : 0.f;
    const float w11 = (vy1 && vx1) ? ly * lx : 0.f;
    _Float16 h00 = (_Float16)w00, h01 = (_Float16)w01;
    _Float16 h10 = (_Float16)w10, h11 = (_Float16)w11;
    t.W00.x = h00; t.W00.y = h00;  t.W01.x = h01; t.W01.y = h01;
    t.W10.x = h10; t.W10.y = h10;  t.W11.x = h11; t.W11.y = h11;
    const int y0c = min(max(y0, 0), Hh - 1), y1c = min(max(y1, 0), Hh - 1);
    const int x0c = min(max(x0, 0), Ww - 1), x1c = min(max(x1, 0), Ww - 1);
    t.a00 = (y0c * Ww + x0c) * 8 + cg;   // 8 uint4/pos; cg = 1 uint4 (8ch)
    t.a01 = (y0c * Ww + x1c) * 8 + cg;
    t.a10 = (y1c * Ww + x0c) * 8 + cg;
    t.a11 = (y1c * Ww + x1c) * 8 + cg;
}

__device__ __forceinline__ void tap_load(const uint4* __restrict__ xb4, const Tap& t,
                                         unsigned (&pf)[16]) {
    *(uint4*)&pf[0]  = xb4[t.a00];
    *(uint4*)&pf[4]  = xb4[t.a01];
    *(uint4*)&pf[8]  = xb4[t.a10];
    *(uint4*)&pf[12] = xb4[t.a11];
}

// weight a-fragments, fragment-major layout: 4 x contiguous-1KB wave loads.
// Wave-pair duplication is L1-broadcast (proven free by the nowt ablation).
__device__ __forceinline__ void wf_load(const unsigned short* __restrict__ wt,
                                        half8 (&WF)[4]) {
    WF[0] = *(const half8*)(wt);             // j0 = (g0, mi0)
    WF[1] = *(const half8*)(wt + 512);       // j1 = (g0, mi1)
    WF[2] = *(const half8*)(wt + 1024);      // j2 = (g1, mi0)
    WF[3] = *(const half8*)(wt + 1536);      // j3 = (g1, mi1)
}

__device__ __forceinline__ void tap_store(const Tap& t, const unsigned (&pf)[16],
                                          unsigned short* __restrict__ vrow) {
    unsigned o[4];
#pragma unroll
    for (int s = 0; s < 4; ++s) {
        half2v v = (*(const half2v*)&pf[s])      * t.W00
                 + (*(const half2v*)&pf[4 + s])  * t.W01
                 + (*(const half2v*)&pf[8 + s])  * t.W10
                 + (*(const half2v*)&pf[12 + s]) * t.W11;
        o[s] = *(unsigned*)&v;
    }
    uint4 u; u.x = o[0]; u.y = o[1]; u.z = o[2]; u.w = o[3];
    *(uint4*)vrow = u;   // single ds_write_b128 (8 channels)
}

__device__ __forceinline__ void mfma_tap(const half8 (&WF)[4],
                                         const unsigned short* __restrict__ Vbuf,
                                         int nt, int ln, floatx4 (&acc)[2]) {
#pragma unroll
    for (int g = 0; g < 2; ++g) {
        const int pp = nt * 16 + (ln & 15);
        half8 bfrag = *(const half8*)&Vbuf[pp * VP + g * 32 + (ln >> 4) * 8];
        acc[0] = __builtin_amdgcn_mfma_f32_16x16x32_f16(WF[2 * g],     bfrag, acc[0], 0, 0, 0);
        acc[1] = __builtin_amdgcn_mfma_f32_16x16x32_f16(WF[2 * g + 1], bfrag, acc[1], 0, 0, 0);
    }
}

// 2-deep gather pipeline, per-tap lgkm barrier (verified best structure).
template<int KT>
__device__ __forceinline__ void pipe_iter(
    const uint4* __restrict__ xb4, const float* __restrict__ offb,
    const unsigned short* __restrict__ wfb,
    const unsigned short* __restrict__ V0, const unsigned short* __restrict__ V1,
    unsigned short* __restrict__ vrow0, unsigned short* __restrict__ vrow1,
    int h, int w, int cg, int nt, int ln,
    Tap& tpA, Tap& tpB, Tap& tpC,
    unsigned (&pfA)[16], unsigned (&pfB)[16], unsigned (&pfC)[16],
    half8 (&WF0)[4], half8 (&WF1)[4],
    float& dy0, float& dx0, float& dy1, float& dx1,
    floatx4 (&acc)[2])
{
    constexpr int S = KT & 1;        // parity of tap KT (store side)
    // 1. weight frags for tap KT (fragment-major: KT*4096 shorts)
    wf_load(wfb + KT * 4096, S ? WF1 : WF0);
    // 2. setup & issue gathers for tap KT+2 ((KT+2)&1 == S -> offset slot S)
    if constexpr (KT + 2 <= 8) {
        constexpr int GI = (KT + 2) % 3;
        Tap& tg = sel3t<GI>(tpA, tpB, tpC);
        tap_setup(KT + 2, h, w, S ? dy1 : dy0, S ? dx1 : dx0, cg, tg);
        tap_load(xb4, tg, sel3<GI>(pfA, pfB, pfC));
    }
    // 3. offset refill for tap KT+4 into slot S
    if constexpr (KT + 4 <= 8) {
        (S ? dy1 : dy0) = offb[(2 * (KT + 4)) * HW];
        (S ? dx1 : dx0) = offb[(2 * (KT + 4) + 1) * HW];
    }
    // 4. MFMA tap KT-1 (parity 1-S): weights and V from last iteration
    constexpr int Tm = 1 - S;
    mfma_tap(Tm ? WF1 : WF0, Tm ? V1 : V0, nt, ln, acc);
    // 5. combine+pack tap KT into V[S] (pf/tp slot KT%3, gathered 2 iters ago)
    constexpr int SI = KT % 3;
    tap_store(sel3t<SI>(tpA, tpB, tpC), sel3<SI>(pfA, pfB, pfC),
              S ? vrow1 : vrow0);
    // 6. barrier (lgkm only; VMEM prefetches stay in flight)
    lds_barrier();
}

__launch_bounds__(256, 4)
__global__ void dcn_mfma(const _Float16* __restrict__ xn,   // NHWC fp16
                         const float* __restrict__ offset,
                         const unsigned short* __restrict__ wb,
                         const float* __restrict__ bias,
                         float* __restrict__ out) {
    __shared__ unsigned short V[2][32 * VP];   // 2 x 4736 B

    const int tid = threadIdx.x;
    const int p   = tid >> 3;     // position (gather role): 8 lanes share one pos
    const int cg  = tid & 7;      // channel chunk 8ch = 16B
    const int wv  = tid >> 6;     // wave id (MFMA role)
    const int ln  = tid & 63;

    const int b  = blockIdx.z;
    const int h  = blockIdx.y;
    const int w0 = blockIdx.x * 32;
    const int w  = w0 + p;

    const uint4* xb4  = (const uint4*)(xn + (size_t)b * HW * 64);
    const float* offb = offset + b * 18 * HW + h * Ww + w;
    unsigned short* vrow0 = &V[0][p * VP + cg * 8];
    unsigned short* vrow1 = &V[1][p * VP + cg * 8];

    const int nt = wv & 1;
    const int mb = (wv >> 1) * 2;
    // fragment-major weight base: region (mbh = wv>>1) + lane offset
    const unsigned short* wfb = wb + (wv >> 1) * 2048 + ln * 8;

    floatx4 acc[2];
    acc[0] = (floatx4)0.f; acc[1] = (floatx4)0.f;

    unsigned pfA[16], pfB[16], pfC[16];
    half8 WF0[4], WF1[4];
    Tap tpA, tpB, tpC;

    // prologue: taps 0,1,2 gathered (slots A,B,C); offsets through tap 4.
    float dy0 = offb[0],        dx0 = offb[HW];         // tap0 -> slot0
    float dy1 = offb[2 * HW],   dx1 = offb[3 * HW];     // tap1 -> slot1
    wf_load(wfb, WF0);                                  // WF(0)
    tap_setup(0, h, w, dy0, dx0, cg, tpA);
    tap_load(xb4, tpA, pfA);
    tap_setup(1, h, w, dy1, dx1, cg, tpB);
    tap_load(xb4, tpB, pfB);
    dy0 = offb[4 * HW]; dx0 = offb[5 * HW];             // tap2 -> slot0
    dy1 = offb[6 * HW]; dx1 = offb[7 * HW];             // tap3 -> slot1
    tap_setup(2, h, w, dy0, dx0, cg, tpC);
    tap_load(xb4, tpC, pfC);
    dy0 = offb[8 * HW]; dx0 = offb[9 * HW];             // tap4 -> slot0
    tap_store(tpA, pfA, vrow0);            // waits G(0); G(1),G(2) in flight
    lds_barrier();

#define PI(K) pipe_iter<K>(xb4, offb, wfb, V[0], V[1], vrow0, vrow1, h, w, cg, nt, ln, \
                           tpA, tpB, tpC, pfA, pfB, pfC, WF0, WF1,                     \
                           dy0, dx0, dy1, dx1, acc)
    PI(1); PI(2); PI(3); PI(4); PI(5); PI(6); PI(7); PI(8);
#undef PI

    // epilogue: tap 8 MFMA (WF0 = tap8 loaded at PI(8), V[0] stored at PI(8))
    mfma_tap(WF0, V[0], nt, ln, acc);

    // epilogue: C/D layout col=lane&15 (pos), row=(lane>>4)*4+reg (o)
    float* outp = out + b * COUT * HW + h * Ww;
    const int col = w0 + nt * 16 + (ln & 15);
#pragma unroll
    for (int mi = 0; mi < 2; ++mi)
#pragma unroll
        for (int r = 0; r < 4; ++r) {
            const int o = (mb + mi) * 16 + (ln >> 4) * 4 + r;
            outp[o * HW + col] = acc[mi][r] + bias[o];
        }
}

extern "C" void kernel_launch(void* const* d_in, const int* in_sizes, int n_in,
                              void* d_out, int out_size, void* d_ws, size_t ws_size,
                              hipStream_t stream) {
    const float* x      = (const float*)d_in[0];
    const float* offset = (const float*)d_in[1];
    const float* weight = (const float*)d_in[2];
    const float* bias   = (const float*)d_in[3];
    float* out = (float*)d_out;

    _Float16* xn = (_Float16*)d_ws;                          // 16.8 MiB NHWC fp16
    unsigned short* wb = (unsigned short*)((char*)d_ws + (size_t)Bb * HW * Cc * 2);

    prep<<<dim3(1024), 512, 0, stream>>>(x, weight, xn, wb);
    dcn_mfma<<<dim3(Ww / 32, Hh, Bb), 256, 0, stream>>>(xn, offset, wb, bias, out);
}